// Round 6
// baseline (312.996 us; speedup 1.0000x reference)
//
#include <hip/hip_runtime.h>
#include <math.h>

#define EPS_GS 1e-8f
#define RAD2DEG 57.29577951308232f
#define PI_F 3.14159265358979f

constexpr int THREADS   = 256;
constexpr int TILE_ROTS = 256;                    // 1 rotation per thread per tile
constexpr int TILE_F    = TILE_ROTS * 9;          // 2304 floats per array per tile
constexpr int WAVE_F    = 64 * 9;                 // 576 floats per wave per array (2304 B)
constexpr int NSLOTS    = 16;                     // atomic spread slots (64B stride)
constexpr int MAX_BLKS  = 1024;                   // 4 resident blocks x 256 CUs

__device__ __forceinline__ float clip10(float x) {
    // ternary form preserves NaN (matches jnp.clip NaN propagation)
    x = x < -10.f ? -10.f : x;
    x = x >  10.f ?  10.f : x;
    return x;
}

// v_sqrt_f32 / v_rcp_f32 — ~1 ulp, single-instruction
__device__ __forceinline__ float fsqrt(float x) { return __builtin_amdgcn_sqrtf(x); }
__device__ __forceinline__ float frcp(float x)  { return __builtin_amdgcn_rcpf(x); }

// async global->LDS. LDS dest = wave-uniform base + lane*width.
__device__ __forceinline__ void gload_lds16(const float* g, float* l) {
    __builtin_amdgcn_global_load_lds(
        (const __attribute__((address_space(1))) void*)g,
        (__attribute__((address_space(3))) void*)l,
        16, 0, 0);
}
__device__ __forceinline__ void gload_lds4(const float* g, float* l) {
    __builtin_amdgcn_global_load_lds(
        (const __attribute__((address_space(1))) void*)g,
        (__attribute__((address_space(3))) void*)l,
        4, 0, 0);
}

// Abramowitz-Stegun 4.4.45: max error 6.76e-5 rad on [-1,1]
__device__ __forceinline__ float fast_acos(float x) {
    float ax = fabsf(x);
    float p = fmaf(ax, -0.0187293f, 0.0742610f);
    p = fmaf(ax, p, -0.2121144f);
    p = fmaf(ax, p, 1.5707288f);
    float pos = fsqrt(1.f - ax) * p;
    return x >= 0.f ? pos : PI_F - pos;
}

// v: 3x3 row-major (clipped). Columns: c0=(v0,v3,v6), c1=(v1,v4,v7), c2=(v2,v5,v8).
// R: row-major rotation, columns e1,e2,e3 (e3 sign-fixed by det).
__device__ __forceinline__ void gs_rotmat(const float* v, float* R) {
    float c0x = v[0], c0y = v[3], c0z = v[6];
    float c1x = v[1], c1y = v[4], c1z = v[7];
    float c2x = v[2], c2y = v[5], c2z = v[8];

    float s1 = fmaf(c0x, c0x, fmaf(c0y, c0y, c0z*c0z));
    float inv1 = frcp(fsqrt(s1) + EPS_GS);
    float e1x = c0x*inv1, e1y = c0y*inv1, e1z = c0z*inv1;

    float d = fmaf(e1x, c1x, fmaf(e1y, c1y, e1z*c1z));
    float u2x = fmaf(-d, e1x, c1x), u2y = fmaf(-d, e1y, c1y), u2z = fmaf(-d, e1z, c1z);
    float s2 = fmaf(u2x, u2x, fmaf(u2y, u2y, u2z*u2z));
    float inv2 = frcp(fsqrt(s2) + EPS_GS);
    float e2x = u2x*inv2, e2y = u2y*inv2, e2z = u2z*inv2;

    float d1 = fmaf(e1x, c2x, fmaf(e1y, c2y, e1z*c2z));
    float d2 = fmaf(e2x, c2x, fmaf(e2y, c2y, e2z*c2z));
    float u3x = fmaf(-d1, e1x, fmaf(-d2, e2x, c2x));
    float u3y = fmaf(-d1, e1y, fmaf(-d2, e2y, c2y));
    float u3z = fmaf(-d1, e1z, fmaf(-d2, e2z, c2z));
    float s3 = fmaf(u3x, u3x, fmaf(u3y, u3y, u3z*u3z));
    float inv3 = frcp(fsqrt(s3) + EPS_GS);
    float e3x = u3x*inv3, e3y = u3y*inv3, e3z = u3z*inv3;

    // det(Q) = e1 . (e2 x e3)
    float cxx = e2y*e3z - e2z*e3y;
    float cxy = e2z*e3x - e2x*e3z;
    float cxz = e2x*e3y - e2y*e3x;
    float det = fmaf(e1x, cxx, fmaf(e1y, cxy, e1z*cxz));
    if (det < 0.f) { e3x = -e3x; e3y = -e3y; e3z = -e3z; } // NaN<0 false -> keep

    R[0] = e1x; R[1] = e2x; R[2] = e3x;
    R[3] = e1y; R[4] = e2y; R[5] = e3y;
    R[6] = e1z; R[7] = e2z; R[8] = e3z;
}

__device__ __forceinline__ void accum_rot(const float* pr, const float* tg,
                                          float& lt, float& lf) {
    float pc[9], tc[9];
    #pragma unroll
    for (int m = 0; m < 9; ++m) { pc[m] = clip10(pr[m]); tc[m] = clip10(tg[m]); }

    float Rp[9], Rt[9];
    gs_rotmat(pc, Rp);
    gs_rotmat(tc, Rt);

    float chord = 0.f, tr = 0.f;
    #pragma unroll
    for (int m = 0; m < 9; ++m) {
        float d = Rp[m] - Rt[m];
        chord = fmaf(d, d, chord);
        tr    = fmaf(Rp[m], Rt[m], tr);
    }

    const float trLo = -3.0f + 1e-6f, trHi = 3.0f - 1e-6f;
    tr = tr < trLo ? trLo : (tr > trHi ? trHi : tr);
    float ca = (tr - 1.f) * 0.5f;
    const float cLo = -1.0f + 1e-7f, cHi = 1.0f - 1e-7f;
    ca = ca < cLo ? cLo : (ca > cHi ? cHi : ca);
    float ang = fast_acos(ca) * RAD2DEG;
    if (ang != ang) ang = 180.f;

    // orthogonality: AtA[i][j] = col_i . col_j of clipped pred matrix.
    // AtA symmetric: diag once, off-diag counted twice.
    float o = 0.f;
    #pragma unroll
    for (int i = 0; i < 3; ++i) {
        float dii = fmaf(pc[i], pc[i], fmaf(pc[3+i], pc[3+i], pc[6+i]*pc[6+i])) - 1.f;
        o = fmaf(dii, dii, o);
    }
    #pragma unroll
    for (int i = 0; i < 3; ++i) {
        #pragma unroll
        for (int j = i + 1; j < 3; ++j) {
            float s = fmaf(pc[i], pc[j], fmaf(pc[3+i], pc[3+j], pc[6+i]*pc[6+j]));
            float s2 = s + s;
            o = fmaf(s2, s, o);
        }
    }

    float l2 = 0.f, fb = 0.f;
    #pragma unroll
    for (int m = 0; m < 9; ++m) {
        l2 = fmaf(pc[m], pc[m], l2);
        float d = pc[m] - tg[m];   // fallback uses UNclipped target
        fb = fmaf(d, d, fb);
    }

    lt += fmaf(0.1f, ang, chord) + fmaf(0.01f, o, (1e-4f/9.f)*l2);
    lf += fb;
}

// BARRIER-FREE per-wave pipeline. r2/r4/r5 all plateaued at ~120us and an
// L3-warm dispatch (hbm_bytes=65KB) was ALSO 118us -> on-chip serialization,
// not bandwidth: compiler-inserted vmcnt(0) before ds_read (gload_lds/ds_read
// alias paranoia) drained the next tile's loads -> no overlap; barriers coupled
// waves. Here each wave owns a private double-buffered LDS region holding
// exactly its 64 rotations, staged by its own 6 gload_lds (2x16B + 1x4B per
// array). Loop: vmcnt(0) (own loads, issued one math-phase earlier) ->
// ds_read own 18 floats -> fence (reads pinned before next stage issue) ->
// stage next tile -> math. No inter-wave data flow -> zero in-loop barriers ->
// 16 independent wave-pipelines per CU.
__global__ __launch_bounds__(THREADS, 4)
void rot_loss_kernel(const float* __restrict__ pred, const float* __restrict__ targ,
                     double* __restrict__ acc, int B) {
    // [buf][wave][pred/targ][576 floats]; per-wave region is wave-private.
    __shared__ alignas(16) float buf[2][4][2][WAVE_F];
    __shared__ float rsum_t[4], rsum_f[4];

    const int tid    = threadIdx.x;
    const int wv     = tid >> 6;          // wave id 0..3 (uniform within wave)
    const int lane   = tid & 63;
    const int ntiles = (B + TILE_ROTS - 1) / TILE_ROTS;
    const int tstep  = gridDim.x;

    float lt = 0.f, lf = 0.f;

    auto tile_full = [&](int t) {
        return (size_t)(t + 1) * TILE_ROTS <= (size_t)B;
    };
    // stage THIS wave's 576+576 floats of tile t into buf[b][wv]:
    // 2 x w16 (256 floats each) + 1 x w4 (64 floats) per array.
    auto stage = [&](int b, int t) {
        const float* ps = pred + (size_t)t * TILE_F + (size_t)wv * WAVE_F;
        const float* qs = targ + (size_t)t * TILE_F + (size_t)wv * WAVE_F;
        float* dp = &buf[b][wv][0][0];
        float* dq = &buf[b][wv][1][0];
        gload_lds16(ps +       lane*4, dp);
        gload_lds16(ps + 256 + lane*4, dp + 256);
        gload_lds4 (ps + 512 + lane,   dp + 512);
        gload_lds16(qs +       lane*4, dq);
        gload_lds16(qs + 256 + lane*4, dq + 256);
        gload_lds4 (qs + 512 + lane,   dq + 512);
    };

    const int t0 = blockIdx.x;
    int cur = 0;
    if (t0 < ntiles && tile_full(t0)) stage(0, t0);   // prologue prefetch

    for (int t = t0; t < ntiles; t += tstep) {
        if (tile_full(t)) {
            // own 6 loads for tile t were issued one full math-phase ago
            asm volatile("s_waitcnt vmcnt(0)" ::: "memory");
            float a1[9], b1[9];
            #pragma unroll
            for (int m = 0; m < 9; ++m) a1[m] = buf[cur][wv][0][lane*9 + m];
            #pragma unroll
            for (int m = 0; m < 9; ++m) b1[m] = buf[cur][wv][1][lane*9 + m];
            // pin: ds_reads issue BEFORE next stage (so any compiler-inserted
            // vmcnt(0) before them has nothing extra to wait for)
            asm volatile("" ::: "memory");
            const int tn = t + tstep;
            if (tn < ntiles && tile_full(tn)) stage(cur ^ 1, tn);
            // math overlaps the in-flight next-tile loads
            accum_rot(a1, b1, lt, lf);
            cur ^= 1;
        } else {
            // partial tail tile: direct loads, correctness only (no barriers)
            const size_t rot0 = (size_t)t * TILE_ROTS;
            const int rem = (int)((size_t)B - rot0);
            for (int r = tid; r < rem; r += THREADS) {
                float a1[9], b1[9];
                const float* pp = pred + (rot0 + r) * 9;
                const float* qq = targ + (rot0 + r) * 9;
                for (int m = 0; m < 9; ++m) { a1[m] = pp[m]; b1[m] = qq[m]; }
                accum_rot(a1, b1, lt, lf);
            }
        }
    }

    // wave-64 reduce
    #pragma unroll
    for (int off = 32; off > 0; off >>= 1) {
        lt += __shfl_down(lt, off, 64);
        lf += __shfl_down(lf, off, 64);
    }
    if (lane == 0) { rsum_t[wv] = lt; rsum_f[wv] = lf; }
    __syncthreads();
    if (tid == 0) {
        float bt = rsum_t[0] + rsum_t[1] + rsum_t[2] + rsum_t[3];
        float bf = rsum_f[0] + rsum_f[1] + rsum_f[2] + rsum_f[3];
        // spread atomics over 16 cache-line-strided slots to avoid
        // same-address f64 atomic serialization at the coherence point
        double* slot = acc + (size_t)(blockIdx.x & (NSLOTS - 1)) * 8;
        unsafeAtomicAdd(&slot[0], (double)bt);  // HW global_atomic_add_f64
        unsafeAtomicAdd(&slot[1], (double)bf);
    }
}

__global__ void finalize_kernel(const double* __restrict__ acc,
                                float* __restrict__ out, int B) {
    if (threadIdx.x == 0 && blockIdx.x == 0) {
        double t = 0.0, f = 0.0;
        for (int s = 0; s < NSLOTS; ++s) { t += acc[s*8]; f += acc[s*8 + 1]; }
        double total = t / (double)B;
        double fb    = f / (9.0 * (double)B);
        out[0] = isnan(total) ? (float)fb : (float)total;
    }
}

extern "C" void kernel_launch(void* const* d_in, const int* in_sizes, int n_in,
                              void* d_out, int out_size, void* d_ws, size_t ws_size,
                              hipStream_t stream) {
    const float* pred = (const float*)d_in[0];
    const float* targ = (const float*)d_in[1];
    const int n = in_sizes[0];
    const int B = n / 9;

    double* acc = (double*)d_ws;
    hipMemsetAsync(d_ws, 0, NSLOTS * 8 * sizeof(double), stream);

    const int ntiles = (B + TILE_ROTS - 1) / TILE_ROTS;
    const int blocks = ntiles < MAX_BLKS ? ntiles : MAX_BLKS;
    rot_loss_kernel<<<blocks, THREADS, 0, stream>>>(pred, targ, acc, B);
    finalize_kernel<<<1, 64, 0, stream>>>(acc, (float*)d_out, B);
}